// Round 4
// baseline (340.199 us; speedup 1.0000x reference)
//
#include <hip/hip_runtime.h>
#include <stdint.h>

#define D_MODEL 256
#define NHEAD   8
#define HDIM    32
#define BATCH   4
#define SEQ     2048
#define MTOT    (BATCH*SEQ)   // 8192 rows

typedef float f32x4 __attribute__((ext_vector_type(4)));
typedef short s16x8 __attribute__((ext_vector_type(8)));

// fp32 -> bf16 (RNE)
__device__ __forceinline__ unsigned short f2bf(float f) {
    union { float f; uint32_t u; } v; v.f = f;
    uint32_t u = v.u;
    u += 0x7fffu + ((u >> 16) & 1u);
    return (unsigned short)(u >> 16);
}

// packed f32x2 -> bf16x2 (lo = a, hi = b)
__device__ __forceinline__ uint32_t cvtpk_bf16(float a, float b) {
    uint32_t r;
    asm("v_cvt_pk_bf16_f32 %0, %1, %2" : "=v"(r) : "v"(a), "v"(b));
    return r;
}

// load 8 consecutive fp32, convert to a bf16 MFMA fragment (s16x8)
__device__ __forceinline__ s16x8 ldfrag_f32(const float* p) {
    f32x4 a = *(const f32x4*)p;
    f32x4 b = *(const f32x4*)(p + 4);
    union { uint32_t u[4]; s16x8 v; } r;
    r.u[0] = cvtpk_bf16(a[0], a[1]);
    r.u[1] = cvtpk_bf16(a[2], a[3]);
    r.u[2] = cvtpk_bf16(b[0], b[1]);
    r.u[3] = cvtpk_bf16(b[2], b[3]);
    return r.v;
}

// ---------------------------------------------------------------------------
// Pack mask [B,1,S,S] int32 -> bitmask. One u64 per (b, q, 64-key chunk).
// ---------------------------------------------------------------------------
__global__ void pack_mask(const int* __restrict__ mask,
                          unsigned long long* __restrict__ pm) {
    const int lane = threadIdx.x & 63;
    const int wid  = (blockIdx.x * blockDim.x + threadIdx.x) >> 6;
    const int nw   = (gridDim.x * blockDim.x) >> 6;
    const int nchunks = BATCH * SEQ * (SEQ / 64);
    for (int c = wid; c < nchunks; c += nw) {
        int v = mask[(size_t)c * 64 + lane];
        unsigned long long bits = __ballot(v != 0);
        if (lane == 0) pm[c] = bits;
    }
}

// ---------------------------------------------------------------------------
// Fused Q/K/V projections straight from fp32 (conversion folded into the
// fragment loads -> no prep pass).  y=0: Q -> [bh][s][32] (epilogue scaled
// by csc), y=1: K -> [bh][s][32], y=2: V -> transposed [bh][32][s].
// ---------------------------------------------------------------------------
__global__ __launch_bounds__(256, 3)
void proj3(const float* __restrict__ Xq, const float* __restrict__ Xk,
           const float* __restrict__ Xv,
           const float* __restrict__ Wq, const float* __restrict__ Wk,
           const float* __restrict__ Wv,
           const float* __restrict__ bq, const float* __restrict__ bk,
           const float* __restrict__ bv,
           unsigned short* __restrict__ Qh, unsigned short* __restrict__ Kh,
           unsigned short* __restrict__ Vt, float csc) {
    const int y = blockIdx.y;
    const float* X = (y == 0) ? Xq : (y == 1) ? Xk : Xv;
    const float* W = (y == 0) ? Wq : (y == 1) ? Wk : Wv;
    const float* bias = (y == 0) ? bq : (y == 1) ? bk : bv;
    const float sc = (y == 0) ? csc : 1.0f;

    const int t = threadIdx.x, lane = t & 63, w = t >> 6;
    const int fr = lane & 15, fg = lane >> 4;
    const int m0 = blockIdx.x * 32;
    const int n0w = w * 64;

    f32x4 acc[2][4] = {};

    if (y < 2) {
        // transposed compute: D[n][m] = W . X^T
        #pragma unroll 2
        for (int k0 = 0; k0 < 256; k0 += 32) {
            s16x8 xf[2], wf[4];
            #pragma unroll
            for (int mg = 0; mg < 2; ++mg)
                xf[mg] = ldfrag_f32(X + ((size_t)(m0 + mg*16 + fr) << 8) + k0 + (fg << 3));
            #pragma unroll
            for (int ng = 0; ng < 4; ++ng)
                wf[ng] = ldfrag_f32(W + ((size_t)(n0w + ng*16 + fr) << 8) + k0 + (fg << 3));
            #pragma unroll
            for (int mg = 0; mg < 2; ++mg)
                #pragma unroll
                for (int ng = 0; ng < 4; ++ng)
                    acc[mg][ng] = __builtin_amdgcn_mfma_f32_16x16x32_bf16(
                        wf[ng], xf[mg], acc[mg][ng], 0, 0, 0);
        }
        unsigned short* OUT = (y == 0) ? Qh : Kh;
        #pragma unroll
        for (int mg = 0; mg < 2; ++mg) {
            const int m = m0 + mg*16 + fr;          // D col = m
            const int bb = m >> 11, ss = m & 2047;
            #pragma unroll
            for (int ng = 0; ng < 4; ++ng) {
                const int nb = n0w + ng*16 + fg*4;   // D rows = n (4 consecutive)
                const int hh = nb >> 5, db = nb & 31;
                f32x4 bi = *(const f32x4*)(bias + nb);
                ushort4 o;
                o.x = f2bf((acc[mg][ng][0] + bi[0]) * sc);
                o.y = f2bf((acc[mg][ng][1] + bi[1]) * sc);
                o.z = f2bf((acc[mg][ng][2] + bi[2]) * sc);
                o.w = f2bf((acc[mg][ng][3] + bi[3]) * sc);
                *(ushort4*)(OUT + (((size_t)(bb*8 + hh) * SEQ) + ss) * 32 + db) = o;
            }
        }
    } else {
        // normal compute: D[m][n] = X . W^T -> store transposed per head
        #pragma unroll 2
        for (int k0 = 0; k0 < 256; k0 += 32) {
            s16x8 xf[2], wf[4];
            #pragma unroll
            for (int mg = 0; mg < 2; ++mg)
                xf[mg] = ldfrag_f32(X + ((size_t)(m0 + mg*16 + fr) << 8) + k0 + (fg << 3));
            #pragma unroll
            for (int ng = 0; ng < 4; ++ng)
                wf[ng] = ldfrag_f32(W + ((size_t)(n0w + ng*16 + fr) << 8) + k0 + (fg << 3));
            #pragma unroll
            for (int mg = 0; mg < 2; ++mg)
                #pragma unroll
                for (int ng = 0; ng < 4; ++ng)
                    acc[mg][ng] = __builtin_amdgcn_mfma_f32_16x16x32_bf16(
                        xf[mg], wf[ng], acc[mg][ng], 0, 0, 0);
        }
        #pragma unroll
        for (int mg = 0; mg < 2; ++mg) {
            const int sb = m0 + mg*16 + fg*4;        // D rows = m (4 consecutive s)
            const int bb = sb >> 11, ss = sb & 2047;
            #pragma unroll
            for (int ng = 0; ng < 4; ++ng) {
                const int n = n0w + ng*16 + fr;      // D col = n
                const int hh = n >> 5, dd = n & 31;
                const float bi = bias[n];
                ushort4 o;
                o.x = f2bf(acc[mg][ng][0] + bi);
                o.y = f2bf(acc[mg][ng][1] + bi);
                o.z = f2bf(acc[mg][ng][2] + bi);
                o.w = f2bf(acc[mg][ng][3] + bi);
                *(ushort4*)(Vt + (((size_t)(bb*8 + hh) * 32) + dd) * SEQ + ss) = o;
            }
        }
    }
}

// ---------------------------------------------------------------------------
// Output projection: d_out[m][n] = Ao . Wo^T + bo (Wo fp32 converted inline).
// ---------------------------------------------------------------------------
__global__ __launch_bounds__(256, 3)
void oproj(const unsigned short* __restrict__ Ao, const float* __restrict__ Wo,
           const float* __restrict__ bo, float* __restrict__ out) {
    const int t = threadIdx.x, lane = t & 63, w = t >> 6;
    const int fr = lane & 15, fg = lane >> 4;
    const int m0 = blockIdx.x * 32;
    const int n0w = w * 64;

    f32x4 acc[2][4] = {};
    #pragma unroll 2
    for (int k0 = 0; k0 < 256; k0 += 32) {
        s16x8 xf[2], wf[4];
        #pragma unroll
        for (int mg = 0; mg < 2; ++mg)
            xf[mg] = *(const s16x8*)(Ao + ((size_t)(m0 + mg*16 + fr) << 8) + k0 + (fg << 3));
        #pragma unroll
        for (int ng = 0; ng < 4; ++ng)
            wf[ng] = ldfrag_f32(Wo + ((size_t)(n0w + ng*16 + fr) << 8) + k0 + (fg << 3));
        #pragma unroll
        for (int mg = 0; mg < 2; ++mg)
            #pragma unroll
            for (int ng = 0; ng < 4; ++ng)
                acc[mg][ng] = __builtin_amdgcn_mfma_f32_16x16x32_bf16(
                    wf[ng], xf[mg], acc[mg][ng], 0, 0, 0);
    }
    #pragma unroll
    for (int mg = 0; mg < 2; ++mg) {
        const int m = m0 + mg*16 + fr;
        #pragma unroll
        for (int ng = 0; ng < 4; ++ng) {
            const int nb = n0w + ng*16 + fg*4;
            f32x4 bi = *(const f32x4*)(bo + nb);
            f32x4 vv = acc[mg][ng] + bi;
            *(f32x4*)(out + (size_t)m * 256 + nb) = vv;
        }
    }
}

// ---------------------------------------------------------------------------
// Flash attention with K-split (blockIdx.z halves the key range -> 2x waves
// for latency hiding). Swapped-QK mfma, mask applied post-exp, speculative
// exp2 with deferred-max rescale (THR=8 in log2 units). Partial (acc, m, l)
// written to ws; combine kernel merges the two halves.
// ---------------------------------------------------------------------------
struct TR {
    s16x8 kf[4];
    s16x8 vf[2][2];
    unsigned long long mw[2];
};

__device__ __forceinline__ void load_tile(TR& tr, int ti,
        const unsigned short* Kb, const unsigned short* Vb,
        const unsigned long long* pm0, const unsigned long long* pm1,
        int fr, int fg) {
    tr.mw[0] = pm0[ti];
    tr.mw[1] = pm1[ti];
    #pragma unroll
    for (int g = 0; g < 4; ++g)   // A-frag rows = keys ti*64+g*16+fr
        tr.kf[g] = *(const s16x8*)(Kb + ((ti*64 + g*16 + fr) << 5) + (fg << 3));
    #pragma unroll
    for (int c = 0; c < 2; ++c)   // A-frag rows = dims hh*16+fr, k = keys c*32+fg*8
        #pragma unroll
        for (int hh = 0; hh < 2; ++hh)
            tr.vf[c][hh] = *(const s16x8*)(Vb + ((hh*16 + fr) << 11) + ti*64 + c*32 + (fg << 3));
}

__device__ __forceinline__ void compute_tile(const TR& tr, const s16x8* qf,
        f32x4 acc[2][2], float* mrun, float* lrun, char* ptb, int fr, int fg) {
    #pragma unroll
    for (int j = 0; j < 2; ++j) {
        const unsigned long long wsh = tr.mw[j] >> (fg * 4);
        const uint32_t wlo = (uint32_t)wsh, whi = (uint32_t)(wsh >> 32);
        f32x4 s[4];
        #pragma unroll
        for (int g = 0; g < 4; ++g) {
            const f32x4 cz = {0.0f, 0.0f, 0.0f, 0.0f};
            s[g] = __builtin_amdgcn_mfma_f32_16x16x32_bf16(tr.kf[g], qf[j], cz, 0, 0, 0);
        }
        float v[16];
        #pragma unroll
        for (int g = 0; g < 4; ++g)
            #pragma unroll
            for (int r = 0; r < 4; ++r)
                v[g*4 + r] = s[g][r];

        // speculative exp with the OLD running max (no wait on the max tree)
        float p[16];
        #pragma unroll
        for (int i = 0; i < 16; ++i) p[i] = exp2f(v[i] - mrun[j]);

        // raw tile max (mask-agnostic upper bound: any reference works)
        float t8[8];
        #pragma unroll
        for (int i = 0; i < 8; ++i) t8[i] = fmaxf(v[2*i], v[2*i+1]);
        float mx = fmaxf(fmaxf(fmaxf(t8[0], t8[1]), fmaxf(t8[2], t8[3])),
                         fmaxf(fmaxf(t8[4], t8[5]), fmaxf(t8[6], t8[7])));
        mx = fmaxf(mx, __shfl_xor(mx, 16));
        mx = fmaxf(mx, __shfl_xor(mx, 32));

        // mask post-exp: zero the masked p's
        #pragma unroll
        for (int g = 0; g < 4; ++g) {
            const uint32_t wsel = (g < 2) ? wlo : whi;
            #pragma unroll
            for (int r = 0; r < 4; ++r)
                p[g*4 + r] = ((wsel >> ((g & 1) * 16 + r)) & 1u) ? p[g*4 + r] : 0.0f;
        }

        if (!__all(mx <= mrun[j] + 8.0f)) {
            // rare path: redo exp with the new reference and rescale state
            const float mn = fmaxf(mrun[j], mx);
            const float rs = exp2f(mrun[j] - mn);
            #pragma unroll
            for (int i = 0; i < 16; ++i) p[i] = exp2f(v[i] - mn);
            #pragma unroll
            for (int g = 0; g < 4; ++g) {
                const uint32_t wsel = (g < 2) ? wlo : whi;
                #pragma unroll
                for (int r = 0; r < 4; ++r)
                    p[g*4 + r] = ((wsel >> ((g & 1) * 16 + r)) & 1u) ? p[g*4 + r] : 0.0f;
            }
            mrun[j] = mn;
            lrun[j] *= rs;
            acc[j][0] *= rs;
            acc[j][1] *= rs;
        }

        float s8[8];
        #pragma unroll
        for (int i = 0; i < 8; ++i) s8[i] = p[2*i] + p[2*i+1];
        float sum = ((s8[0]+s8[1]) + (s8[2]+s8[3])) + ((s8[4]+s8[5]) + (s8[6]+s8[7]));
        sum += __shfl_xor(sum, 16);
        sum += __shfl_xor(sum, 32);
        lrun[j] += sum;

        // P -> per-wave LDS (XOR-swizzled 128B rows), re-read as B-frags.
        // Same-wave DS ops complete in order; no barrier needed.
        char* row = ptb + (j << 11) + fr * 128;
        #pragma unroll
        for (int g = 0; g < 4; ++g) {
            const uint32_t p0 = cvtpk_bf16(p[g*4+0], p[g*4+1]);
            const uint32_t p1 = cvtpk_bf16(p[g*4+2], p[g*4+3]);
            const int slot = (g*2 + (fg >> 1)) ^ (fr & 7);
            *(uint2*)(row + (slot << 4) + ((fg & 1) << 3)) = make_uint2(p0, p1);
        }
        #pragma unroll
        for (int c = 0; c < 2; ++c) {
            const int slot = (c*4 + fg) ^ (fr & 7);
            const s16x8 pb = *(const s16x8*)(row + (slot << 4));
            #pragma unroll
            for (int hh = 0; hh < 2; ++hh)
                acc[j][hh] = __builtin_amdgcn_mfma_f32_16x16x32_bf16(
                    tr.vf[c][hh], pb, acc[j][hh], 0, 0, 0);
        }
    }
}

__global__ __launch_bounds__(256, 4)
void attn_fused(const unsigned short* __restrict__ Qh,
                const unsigned short* __restrict__ Kh,
                const unsigned short* __restrict__ Vt,
                const unsigned long long* __restrict__ pm,
                float* __restrict__ Opart, float2* __restrict__ MLpart) {
    __shared__ __align__(16) char ptbuf[16384];   // 4KB per wave
    const int t = threadIdx.x, lane = t & 63, w = t >> 6;
    const int fr = lane & 15, fg = lane >> 4;
    const int by = blockIdx.y, b = by >> 3;
    const int kz = blockIdx.z;                    // key half
    const int q0 = blockIdx.x * 128 + w * 32;
    const unsigned short* Qb = Qh + (size_t)by * SEQ * HDIM;
    const unsigned short* Kb = Kh + (size_t)by * SEQ * HDIM + ((size_t)kz << 15); // kz*1024*32
    const unsigned short* Vb = Vt + (size_t)by * HDIM * SEQ + ((size_t)kz << 10); // kz*1024
    const unsigned long long* pm0 = pm + ((size_t)b * SEQ + q0 + fr) * 32 + kz * 16;
    const unsigned long long* pm1 = pm0 + 16 * 32;
    char* ptb = ptbuf + (w << 12);

    s16x8 qf[2];   // B-frag: col=q, k=d
    #pragma unroll
    for (int j = 0; j < 2; ++j)
        qf[j] = *(const s16x8*)(Qb + ((q0 + j*16 + fr) << 5) + (fg << 3));

    f32x4 acc[2][2] = {};
    float mrun[2] = {-1e20f, -1e20f};
    float lrun[2] = {0.0f, 0.0f};

    TR A, B;
    load_tile(A, 0, Kb, Vb, pm0, pm1, fr, fg);
    #pragma unroll 1
    for (int ti = 0; ti < 16; ti += 2) {
        load_tile(B, ti + 1, Kb, Vb, pm0, pm1, fr, fg);
        compute_tile(A, qf, acc, mrun, lrun, ptb, fr, fg);
        load_tile(A, (ti + 2 < 16) ? ti + 2 : 15, Kb, Vb, pm0, pm1, fr, fg);
        compute_tile(B, qf, acc, mrun, lrun, ptb, fr, fg);
    }

    // write unnormalized partials
    #pragma unroll
    for (int j = 0; j < 2; ++j) {
        const int q = q0 + j*16 + fr;
        const size_t row = ((size_t)(kz*32 + by) * SEQ) + q;
        #pragma unroll
        for (int hh = 0; hh < 2; ++hh)
            *(f32x4*)(Opart + row * 32 + hh*16 + fg*4) = acc[j][hh];
        if (fg == 0)
            MLpart[row] = make_float2(mrun[j], lrun[j]);
    }
}

// ---------------------------------------------------------------------------
// Merge the two K-halves: O = (w1*O1 + w2*O2) / (w1*l1 + w2*l2), bf16 out.
// ---------------------------------------------------------------------------
__global__ __launch_bounds__(256)
void combine(const float* __restrict__ Opart, const float2* __restrict__ ML,
             unsigned short* __restrict__ Ao) {
    const int t = blockIdx.x * 256 + threadIdx.x;   // 524288 = 65536 rows x 8
    const int row = t >> 3, c = t & 7;
    const float2 ml1 = ML[row];
    const float2 ml2 = ML[row + 65536];
    const float m = fmaxf(ml1.x, ml2.x);
    const float w1 = exp2f(ml1.x - m), w2 = exp2f(ml2.x - m);
    const float inv = 1.0f / (w1 * ml1.y + w2 * ml2.y);
    const f32x4 o1 = *(const f32x4*)(Opart + (size_t)row * 32 + c * 4);
    const f32x4 o2 = *(const f32x4*)(Opart + ((size_t)row + 65536) * 32 + c * 4);
    const int bh = row >> 11, q = row & 2047;
    const int b = bh >> 3, h = bh & 7;
    ushort4 o;
    o.x = f2bf((w1 * o1[0] + w2 * o2[0]) * inv);
    o.y = f2bf((w1 * o1[1] + w2 * o2[1]) * inv);
    o.z = f2bf((w1 * o1[2] + w2 * o2[2]) * inv);
    o.w = f2bf((w1 * o1[3] + w2 * o2[3]) * inv);
    *(ushort4*)(Ao + ((size_t)(b * SEQ + q) * 256) + h * 32 + c * 4) = o;
}

// ---------------------------------------------------------------------------
extern "C" void kernel_launch(void* const* d_in, const int* in_sizes, int n_in,
                              void* d_out, int out_size, void* d_ws, size_t ws_size,
                              hipStream_t stream) {
    const float* query = (const float*)d_in[0];
    const float* key   = (const float*)d_in[1];
    const float* value = (const float*)d_in[2];
    const int*   mask  = (const int*)  d_in[3];
    const float* Wq = (const float*)d_in[4];   const float* bq = (const float*)d_in[5];
    const float* Wk = (const float*)d_in[6];   const float* bk = (const float*)d_in[7];
    const float* Wv = (const float*)d_in[8];   const float* bv = (const float*)d_in[9];
    const float* Wo = (const float*)d_in[10];  const float* bo = (const float*)d_in[11];

    char* ws = (char*)d_ws;
    const size_t MB = 1024 * 1024;
    unsigned long long* pmw = (unsigned long long*)(ws);          // 2 MiB
    unsigned short* Qh  = (unsigned short*)(ws + 2*MB);           // 4 MiB
    unsigned short* Kh  = (unsigned short*)(ws + 6*MB);           // 4 MiB
    unsigned short* Vt  = (unsigned short*)(ws + 10*MB);          // 4 MiB
    unsigned short* Aob = (unsigned short*)(ws + 14*MB);          // 4 MiB
    float*  Opart = (float*)(ws + 18*MB);                         // 16 MiB
    float2* MLp   = (float2*)(ws + 34*MB);                        // 1 MiB

    const float csc = (float)(0.17677669529663687 * 1.4426950408889634); // log2e/sqrt(32)

    pack_mask<<<2048, 256, 0, stream>>>(mask, pmw);
    proj3<<<dim3(256, 3), 256, 0, stream>>>(query, key, value, Wq, Wk, Wv,
                                            bq, bk, bv, Qh, Kh, Vt, csc);
    attn_fused<<<dim3(16, 32, 2), 256, 0, stream>>>(Qh, Kh, Vt, pmw, Opart, MLp);
    combine<<<2048, 256, 0, stream>>>(Opart, MLp, Aob);
    oproj<<<256, 256, 0, stream>>>(Aob, Wo, bo, (float*)d_out);
}

// Round 8
// 263.115 us; speedup vs baseline: 1.2930x; 1.2930x over previous
//
#include <hip/hip_runtime.h>
#include <stdint.h>

#define D_MODEL 256
#define NHEAD   8
#define HDIM    32
#define BATCH   4
#define SEQ     2048
#define MTOT    (BATCH*SEQ)   // 8192 rows

typedef float f32x4 __attribute__((ext_vector_type(4)));
typedef short s16x8 __attribute__((ext_vector_type(8)));

// fp32 -> bf16 (RNE)
__device__ __forceinline__ unsigned short f2bf(float f) {
    union { float f; uint32_t u; } v; v.f = f;
    uint32_t u = v.u;
    u += 0x7fffu + ((u >> 16) & 1u);
    return (unsigned short)(u >> 16);
}

// packed f32x2 -> bf16x2 (lo = a, hi = b)
__device__ __forceinline__ uint32_t cvtpk_bf16(float a, float b) {
    uint32_t r;
    asm("v_cvt_pk_bf16_f32 %0, %1, %2" : "=v"(r) : "v"(a), "v"(b));
    return r;
}

// load 8 consecutive fp32, convert to a bf16 MFMA fragment (s16x8)
__device__ __forceinline__ s16x8 ldfrag_f32(const float* p) {
    f32x4 a = *(const f32x4*)p;
    f32x4 b = *(const f32x4*)(p + 4);
    union { uint32_t u[4]; s16x8 v; } r;
    r.u[0] = cvtpk_bf16(a[0], a[1]);
    r.u[1] = cvtpk_bf16(a[2], a[3]);
    r.u[2] = cvtpk_bf16(b[0], b[1]);
    r.u[3] = cvtpk_bf16(b[2], b[3]);
    return r.v;
}

// ---------------------------------------------------------------------------
// Pack mask [B,1,S,S] int32 -> bitmask. One u64 per (b, q, 64-key chunk).
// (verbatim from round-3/round-4 passing modules)
// ---------------------------------------------------------------------------
__global__ void pack_mask(const int* __restrict__ mask,
                          unsigned long long* __restrict__ pm) {
    const int lane = threadIdx.x & 63;
    const int wid  = (blockIdx.x * blockDim.x + threadIdx.x) >> 6;
    const int nw   = (gridDim.x * blockDim.x) >> 6;
    const int nchunks = BATCH * SEQ * (SEQ / 64);
    for (int c = wid; c < nchunks; c += nw) {
        int v = mask[(size_t)c * 64 + lane];
        unsigned long long bits = __ballot(v != 0);
        if (lane == 0) pm[c] = bits;
    }
}

// ---------------------------------------------------------------------------
// Fused Q/K/V projections straight from fp32. VERBATIM the m-32 version that
// PASSED on HW in round 4. m-tile = 32 rows/block, grid dim3(256, 3).
// ---------------------------------------------------------------------------
__global__ __launch_bounds__(256, 3)
void proj3(const float* __restrict__ Xq, const float* __restrict__ Xk,
           const float* __restrict__ Xv,
           const float* __restrict__ Wq, const float* __restrict__ Wk,
           const float* __restrict__ Wv,
           const float* __restrict__ bq, const float* __restrict__ bk,
           const float* __restrict__ bv,
           unsigned short* __restrict__ Qh, unsigned short* __restrict__ Kh,
           unsigned short* __restrict__ Vt, float csc) {
    const int y = blockIdx.y;
    const float* X = (y == 0) ? Xq : (y == 1) ? Xk : Xv;
    const float* W = (y == 0) ? Wq : (y == 1) ? Wk : Wv;
    const float* bias = (y == 0) ? bq : (y == 1) ? bk : bv;
    const float sc = (y == 0) ? csc : 1.0f;

    const int t = threadIdx.x, lane = t & 63, w = t >> 6;
    const int fr = lane & 15, fg = lane >> 4;
    const int m0 = blockIdx.x * 32;
    const int n0w = w * 64;

    f32x4 acc[2][4] = {};

    if (y < 2) {
        // transposed compute: D[n][m] = W . X^T
        #pragma unroll 2
        for (int k0 = 0; k0 < 256; k0 += 32) {
            s16x8 xf[2], wf[4];
            #pragma unroll
            for (int mg = 0; mg < 2; ++mg)
                xf[mg] = ldfrag_f32(X + ((size_t)(m0 + mg*16 + fr) << 8) + k0 + (fg << 3));
            #pragma unroll
            for (int ng = 0; ng < 4; ++ng)
                wf[ng] = ldfrag_f32(W + ((size_t)(n0w + ng*16 + fr) << 8) + k0 + (fg << 3));
            #pragma unroll
            for (int mg = 0; mg < 2; ++mg)
                #pragma unroll
                for (int ng = 0; ng < 4; ++ng)
                    acc[mg][ng] = __builtin_amdgcn_mfma_f32_16x16x32_bf16(
                        wf[ng], xf[mg], acc[mg][ng], 0, 0, 0);
        }
        unsigned short* OUT = (y == 0) ? Qh : Kh;
        #pragma unroll
        for (int mg = 0; mg < 2; ++mg) {
            const int m = m0 + mg*16 + fr;          // D col = m
            const int bb = m >> 11, ss = m & 2047;
            #pragma unroll
            for (int ng = 0; ng < 4; ++ng) {
                const int nb = n0w + ng*16 + fg*4;   // D rows = n (4 consecutive)
                const int hh = nb >> 5, db = nb & 31;
                f32x4 bi = *(const f32x4*)(bias + nb);
                ushort4 o;
                o.x = f2bf((acc[mg][ng][0] + bi[0]) * sc);
                o.y = f2bf((acc[mg][ng][1] + bi[1]) * sc);
                o.z = f2bf((acc[mg][ng][2] + bi[2]) * sc);
                o.w = f2bf((acc[mg][ng][3] + bi[3]) * sc);
                *(ushort4*)(OUT + (((size_t)(bb*8 + hh) * SEQ) + ss) * 32 + db) = o;
            }
        }
    } else {
        // normal compute: D[m][n] = X . W^T -> store transposed per head
        #pragma unroll 2
        for (int k0 = 0; k0 < 256; k0 += 32) {
            s16x8 xf[2], wf[4];
            #pragma unroll
            for (int mg = 0; mg < 2; ++mg)
                xf[mg] = ldfrag_f32(X + ((size_t)(m0 + mg*16 + fr) << 8) + k0 + (fg << 3));
            #pragma unroll
            for (int ng = 0; ng < 4; ++ng)
                wf[ng] = ldfrag_f32(W + ((size_t)(n0w + ng*16 + fr) << 8) + k0 + (fg << 3));
            #pragma unroll
            for (int mg = 0; mg < 2; ++mg)
                #pragma unroll
                for (int ng = 0; ng < 4; ++ng)
                    acc[mg][ng] = __builtin_amdgcn_mfma_f32_16x16x32_bf16(
                        xf[mg], wf[ng], acc[mg][ng], 0, 0, 0);
        }
        #pragma unroll
        for (int mg = 0; mg < 2; ++mg) {
            const int sb = m0 + mg*16 + fg*4;        // D rows = m (4 consecutive s)
            const int bb = sb >> 11, ss = sb & 2047;
            #pragma unroll
            for (int ng = 0; ng < 4; ++ng) {
                const int n = n0w + ng*16 + fr;      // D col = n
                const int hh = n >> 5, dd = n & 31;
                const float bi = bias[n];
                ushort4 o;
                o.x = f2bf(acc[mg][ng][0] + bi);
                o.y = f2bf(acc[mg][ng][1] + bi);
                o.z = f2bf(acc[mg][ng][2] + bi);
                o.w = f2bf(acc[mg][ng][3] + bi);
                *(ushort4*)(Vt + (((size_t)(bb*8 + hh) * 32) + dd) * SEQ + ss) = o;
            }
        }
    }
}

// ---------------------------------------------------------------------------
// Output projection. VERBATIM the m-32 version that PASSED in round 4.
// ---------------------------------------------------------------------------
__global__ __launch_bounds__(256, 3)
void oproj(const unsigned short* __restrict__ Ao, const float* __restrict__ Wo,
           const float* __restrict__ bo, float* __restrict__ out) {
    const int t = threadIdx.x, lane = t & 63, w = t >> 6;
    const int fr = lane & 15, fg = lane >> 4;
    const int m0 = blockIdx.x * 32;
    const int n0w = w * 64;

    f32x4 acc[2][4] = {};
    #pragma unroll 2
    for (int k0 = 0; k0 < 256; k0 += 32) {
        s16x8 xf[2], wf[4];
        #pragma unroll
        for (int mg = 0; mg < 2; ++mg)
            xf[mg] = *(const s16x8*)(Ao + ((size_t)(m0 + mg*16 + fr) << 8) + k0 + (fg << 3));
        #pragma unroll
        for (int ng = 0; ng < 4; ++ng)
            wf[ng] = ldfrag_f32(Wo + ((size_t)(n0w + ng*16 + fr) << 8) + k0 + (fg << 3));
        #pragma unroll
        for (int mg = 0; mg < 2; ++mg)
            #pragma unroll
            for (int ng = 0; ng < 4; ++ng)
                acc[mg][ng] = __builtin_amdgcn_mfma_f32_16x16x32_bf16(
                    wf[ng], xf[mg], acc[mg][ng], 0, 0, 0);
    }
    #pragma unroll
    for (int mg = 0; mg < 2; ++mg) {
        const int m = m0 + mg*16 + fr;
        #pragma unroll
        for (int ng = 0; ng < 4; ++ng) {
            const int nb = n0w + ng*16 + fg*4;
            f32x4 bi = *(const f32x4*)(bo + nb);
            f32x4 vv = acc[mg][ng] + bi;
            *(f32x4*)(out + (size_t)m * 256 + nb) = vv;
        }
    }
}

// ---------------------------------------------------------------------------
// Flash attention — VERBATIM the version that PASSED in round 3 (78 us).
// ---------------------------------------------------------------------------
struct TR {
    s16x8 kf[4];
    s16x8 vf[2][2];
    unsigned long long mw[2];
};

__device__ __forceinline__ void load_tile(TR& tr, int ti,
        const unsigned short* Kb, const unsigned short* Vb,
        const unsigned long long* pm0, const unsigned long long* pm1,
        int fr, int fg) {
    tr.mw[0] = pm0[ti];
    tr.mw[1] = pm1[ti];
    #pragma unroll
    for (int g = 0; g < 4; ++g)   // A-frag rows = keys ti*64+g*16+fr
        tr.kf[g] = *(const s16x8*)(Kb + ((ti*64 + g*16 + fr) << 5) + (fg << 3));
    #pragma unroll
    for (int c = 0; c < 2; ++c)   // A-frag rows = dims hh*16+fr, k = keys c*32+fg*8
        #pragma unroll
        for (int hh = 0; hh < 2; ++hh)
            tr.vf[c][hh] = *(const s16x8*)(Vb + ((hh*16 + fr) << 11) + ti*64 + c*32 + (fg << 3));
}

__device__ __forceinline__ void compute_tile(const TR& tr, const s16x8* qf,
        f32x4 acc[2][2], float* mrun, float* lrun, char* ptb, int fr, int fg) {
    #pragma unroll
    for (int j = 0; j < 2; ++j) {
        const unsigned long long wsh = tr.mw[j] >> (fg * 4);
        const uint32_t wlo = (uint32_t)wsh, whi = (uint32_t)(wsh >> 32);
        f32x4 s[4];
        #pragma unroll
        for (int g = 0; g < 4; ++g) {
            const uint32_t wsel = (g < 2) ? wlo : whi;
            f32x4 cm;   // additive mask folded into the MFMA C operand
            #pragma unroll
            for (int r = 0; r < 4; ++r)
                cm[r] = ((wsel >> ((g & 1) * 16 + r)) & 1u) ? 0.0f : -1.0e30f;
            s[g] = __builtin_amdgcn_mfma_f32_16x16x32_bf16(tr.kf[g], qf[j], cm, 0, 0, 0);
        }
        float v[16];
        #pragma unroll
        for (int g = 0; g < 4; ++g)
            #pragma unroll
            for (int r = 0; r < 4; ++r)
                v[g*4 + r] = s[g][r];
        // row max: in-lane tree + 2 cross-fg shuffles
        float t8[8];
        #pragma unroll
        for (int i = 0; i < 8; ++i) t8[i] = fmaxf(v[2*i], v[2*i+1]);
        float mx = fmaxf(fmaxf(fmaxf(t8[0], t8[1]), fmaxf(t8[2], t8[3])),
                         fmaxf(fmaxf(t8[4], t8[5]), fmaxf(t8[6], t8[7])));
        mx = fmaxf(mx, __shfl_xor(mx, 16));
        mx = fmaxf(mx, __shfl_xor(mx, 32));
        const float mn = fmaxf(mrun[j], mx);   // floor -1e20 keeps all-masked tiles inert
        const float rs = exp2f(mrun[j] - mn);
        mrun[j] = mn;
        float p[16];
        #pragma unroll
        for (int i = 0; i < 16; ++i) p[i] = exp2f(v[i] - mn);
        float s8[8];
        #pragma unroll
        for (int i = 0; i < 8; ++i) s8[i] = p[2*i] + p[2*i+1];
        float sum = ((s8[0]+s8[1]) + (s8[2]+s8[3])) + ((s8[4]+s8[5]) + (s8[6]+s8[7]));
        sum += __shfl_xor(sum, 16);
        sum += __shfl_xor(sum, 32);
        lrun[j] = lrun[j] * rs + sum;
        acc[j][0] *= rs;
        acc[j][1] *= rs;
        // P -> per-wave LDS (XOR-swizzled 128B rows), re-read as B-frags.
        // Same-wave DS ops execute in order; no barrier needed.
        char* row = ptb + (j << 11) + fr * 128;
        #pragma unroll
        for (int g = 0; g < 4; ++g) {
            const uint32_t p0 = cvtpk_bf16(p[g*4+0], p[g*4+1]);
            const uint32_t p1 = cvtpk_bf16(p[g*4+2], p[g*4+3]);
            const int slot = (g*2 + (fg >> 1)) ^ (fr & 7);
            *(uint2*)(row + (slot << 4) + ((fg & 1) << 3)) = make_uint2(p0, p1);
        }
        #pragma unroll
        for (int c = 0; c < 2; ++c) {
            const int slot = (c*4 + fg) ^ (fr & 7);
            const s16x8 pb = *(const s16x8*)(row + (slot << 4));
            #pragma unroll
            for (int hh = 0; hh < 2; ++hh)
                acc[j][hh] = __builtin_amdgcn_mfma_f32_16x16x32_bf16(
                    tr.vf[c][hh], pb, acc[j][hh], 0, 0, 0);
        }
    }
}

__global__ __launch_bounds__(256, 2)
void attn_fused(const unsigned short* __restrict__ Qh,
                const unsigned short* __restrict__ Kh,
                const unsigned short* __restrict__ Vt,
                const unsigned long long* __restrict__ pm,
                unsigned short* __restrict__ Ao) {
    __shared__ __align__(16) char ptbuf[16384];   // 4KB per wave (2 q-groups x 2KB)
    const int t = threadIdx.x, lane = t & 63, w = t >> 6;
    const int fr = lane & 15, fg = lane >> 4;
    const int by = blockIdx.y, b = by >> 3, h = by & 7;
    const int q0 = blockIdx.x * 128 + w * 32;
    const unsigned short* Qb = Qh + (size_t)by * SEQ * HDIM;
    const unsigned short* Kb = Kh + (size_t)by * SEQ * HDIM;
    const unsigned short* Vb = Vt + (size_t)by * HDIM * SEQ;
    const unsigned long long* pm0 = pm + ((size_t)b * SEQ + q0 + fr) * 32;
    const unsigned long long* pm1 = pm0 + 16 * 32;
    char* ptb = ptbuf + (w << 12);

    s16x8 qf[2];   // B-frag: col=q, k=d
    #pragma unroll
    for (int j = 0; j < 2; ++j)
        qf[j] = *(const s16x8*)(Qb + ((q0 + j*16 + fr) << 5) + (fg << 3));

    f32x4 acc[2][2] = {};
    float mrun[2] = {-1e20f, -1e20f};
    float lrun[2] = {0.0f, 0.0f};

    TR A, B;
    load_tile(A, 0, Kb, Vb, pm0, pm1, fr, fg);
    #pragma unroll 1
    for (int ti = 0; ti < 32; ti += 2) {
        load_tile(B, ti + 1, Kb, Vb, pm0, pm1, fr, fg);
        compute_tile(A, qf, acc, mrun, lrun, ptb, fr, fg);
        load_tile(A, (ti + 2 < 32) ? ti + 2 : 31, Kb, Vb, pm0, pm1, fr, fg);
        compute_tile(B, qf, acc, mrun, lrun, ptb, fr, fg);
    }

    #pragma unroll
    for (int j = 0; j < 2; ++j) {
        const float inv = 1.0f / lrun[j];
        const int q = q0 + j*16 + fr;
        #pragma unroll
        for (int hh = 0; hh < 2; ++hh) {
            ushort4 o;
            o.x = f2bf(acc[j][hh][0] * inv);
            o.y = f2bf(acc[j][hh][1] * inv);
            o.z = f2bf(acc[j][hh][2] * inv);
            o.w = f2bf(acc[j][hh][3] * inv);
            *(ushort4*)(Ao + (((size_t)b * SEQ + q) * 8 + h) * 32 + hh*16 + fg*4) = o;
        }
    }
}

// ---------------------------------------------------------------------------
extern "C" void kernel_launch(void* const* d_in, const int* in_sizes, int n_in,
                              void* d_out, int out_size, void* d_ws, size_t ws_size,
                              hipStream_t stream) {
    const float* query = (const float*)d_in[0];
    const float* key   = (const float*)d_in[1];
    const float* value = (const float*)d_in[2];
    const int*   mask  = (const int*)  d_in[3];
    const float* Wq = (const float*)d_in[4];   const float* bq = (const float*)d_in[5];
    const float* Wk = (const float*)d_in[6];   const float* bk = (const float*)d_in[7];
    const float* Wv = (const float*)d_in[8];   const float* bv = (const float*)d_in[9];
    const float* Wo = (const float*)d_in[10];  const float* bo = (const float*)d_in[11];

    char* ws = (char*)d_ws;
    const size_t MB = 1024 * 1024;
    unsigned long long* pmw = (unsigned long long*)(ws);          // 2 MiB
    unsigned short* Qh  = (unsigned short*)(ws + 2*MB);           // 4 MiB
    unsigned short* Kh  = (unsigned short*)(ws + 6*MB);           // 4 MiB
    unsigned short* Vt  = (unsigned short*)(ws + 10*MB);          // 4 MiB
    unsigned short* Aob = (unsigned short*)(ws + 14*MB);          // 4 MiB

    const float csc = (float)(0.17677669529663687 * 1.4426950408889634); // log2e/sqrt(32)

    pack_mask<<<2048, 256, 0, stream>>>(mask, pmw);
    proj3<<<dim3(256, 3), 256, 0, stream>>>(query, key, value, Wq, Wk, Wv,
                                            bq, bk, bv, Qh, Kh, Vt, csc);
    attn_fused<<<dim3(16, 32), 256, 0, stream>>>(Qh, Kh, Vt, pmw, Aob);
    oproj<<<256, 256, 0, stream>>>(Aob, Wo, bo, (float*)d_out);
}